// Round 9
// baseline (228.816 us; speedup 1.0000x reference)
//
#include <hip/hip_runtime.h>
#include <stdint.h>

typedef unsigned long long ull;

#define NA 8400
#define NB 32
#define KTOP 300
#define NC 80
#define TB 512         // 8 waves; NO min-waves hint: R8 showed it triggers scratch spill
#define CH 17          // 512*17 = 8704 >= 8400; keys live in registers
#define NBIN 309       // 1 underflow bin + 307 score bins + margin
#define HSTR 311       // odd stride: copies of one bin staggered across banks
#define NCPY 8         // histogram copies (one per wave)
#define BASEK 0xBE4CCCCDu   // bits of 0.2f with sign-flag set (keys are score-bits | 0x80000000)
#define CANDMAX 512

// out layout: boxes_yxyx @0 ; in_zone @38400 ; scores @48000 ; classes @57600 ;
//             centers_yx @67200 ; keep @86400 ; total 96000 floats
#define O1 38400
#define O2 48000
#define O3 57600
#define O4 67200
#define O5 86400

// ---------------- A: per-anchor score key (memory-bound, unchanged) ----------------
__global__ __launch_bounds__(256) void score_kernel(const float* __restrict__ pred,
                                                    uint32_t* __restrict__ keys) {
    __shared__ float sP[128 * 85];
    const int blk = blockIdx.x;                       // 2100 blocks * 128 anchors
    const float4* g4 = (const float4*)(pred + (size_t)blk * 128 * 85);
    float4* l4 = (float4*)sP;
    for (int i = threadIdx.x; i < (128 * 85 / 4); i += 256) l4[i] = g4[i];
    __syncthreads();
    const int t = threadIdx.x;
    if (t < 128) {
        const float* p = sP + t * 85;
        float obj = p[4];
        float b0 = p[5], b1 = p[6], b2 = p[7], b3 = p[8];
        #pragma unroll
        for (int c = 4; c < NC; c += 4) {
            b0 = fmaxf(b0, p[5 + c]);
            b1 = fmaxf(b1, p[6 + c]);
            b2 = fmaxf(b2, p[7 + c]);
            b3 = fmaxf(b3, p[8 + c]);
        }
        float best = fmaxf(fmaxf(b0, b1), fmaxf(b2, b3));
        float sc = obj * best;
        uint32_t u = (sc >= 0.2f) ? (__float_as_uint(sc) | 0x80000000u) : 0x007FFFFFu;
        keys[(size_t)blk * 128 + t] = u;
    }
}

__device__ __forceinline__ uint32_t key_bin(uint32_t k) {
    return (k < BASEK) ? 0u : (1u + ((k - BASEK) >> 16));   // max 308 < NBIN
}

// ---------------- B: one block per batch: select + sort + gather + IoU + NMS ----------------
__global__ __launch_bounds__(TB) void batch_kernel(const float* __restrict__ pred,
                                                   const float* __restrict__ zone,
                                                   const uint32_t* __restrict__ keys,
                                                   float* __restrict__ out) {
    #pragma clang fp contract(off)
    __shared__ uint32_t sH[NCPY * HSTR];
    __shared__ __align__(16) ull sSel[KTOP];
    __shared__ ull sSorted[KTOP];
    __shared__ ull sCand[CANDMAX];
    __shared__ float4 sBox[KTOP];       // (x1,y1,x2,y2) per sorted box
    __shared__ float sA[KTOP];          // precomputed clamped area (same expression as ref)
    __shared__ ull sMask[KTOP * 5];
    __shared__ uint32_t sWTot[8];
    __shared__ uint32_t sBc[2];
    __shared__ uint32_t sPar[KTOP];
    __shared__ ull sKeepF[5];
    __shared__ float sZone[16];
    __shared__ uint32_t sCN;

    const int b = blockIdx.x;
    const int t = threadIdx.x;
    const int lane = t & 63;
    const int wv = t >> 6;              // 0..7; also the histogram copy id

    // ---- coalesced key load into registers (pads -> key 0 -> bin 0, never selected) ----
    uint32_t myk[CH];
    #pragma unroll
    for (int e = 0; e < CH; ++e) {
        int idx = e * TB + t;
        myk[e] = (idx < NA) ? keys[(size_t)b * NA + idx] : 0u;
    }
    for (int i = t; i < NCPY * HSTR; i += TB) sH[i] = 0u;
    if (t < 16) sZone[t] = zone[t];
    __syncthreads();

    // ---- one-shot dense histogram (8 copies, one per wave) ----
    // bin 0 (below-threshold, ~20% of keys, SAME address) via ballot+popc: one atomic/wave
    {
        uint32_t* hw = &sH[wv * HSTR];
        uint32_t c0 = 0;
        #pragma unroll
        for (int e = 0; e < CH; ++e) {
            uint32_t k = myk[e];
            ull m = __ballot(k < BASEK);
            c0 += (uint32_t)__popcll(m);
            if (k >= BASEK)
                atomicAdd(&hw[1u + ((k - BASEK) >> 16)], 1u);
        }
        if (lane == 0) atomicAdd(&hw[0], c0);
    }
    __syncthreads();

    // ---- suffix scan over 309 bins (waves 0..4), find threshold bin ----
    uint32_t v = 0, s = 0;
    if (t < 320) {
        if (t < NBIN) {
            #pragma unroll
            for (int c = 0; c < NCPY; ++c) v += sH[c * HSTR + t];
        }
        s = v;
        #pragma unroll
        for (int off = 1; off < 64; off <<= 1) {
            uint32_t o = __shfl_down(s, off, 64);
            if (lane + off < 64) s += o;
        }
        if (lane == 0) sWTot[wv] = s;
    }
    __syncthreads();
    if (t < 320) {
        uint32_t S = s;
        for (int w2 = wv + 1; w2 < 5; ++w2) S += sWTot[w2];
        uint32_t above = S - v;              // keys in bins strictly above t
        if (above < KTOP && S >= KTOP) {     // unique crossing bin
            sBc[0] = (uint32_t)t;
            sBc[1] = KTOP - above;
        }
    }
    __syncthreads();
    const uint32_t Tbin = sBc[0];
    const uint32_t rem = sBc[1];             // how many to take from bin Tbin
    const uint32_t cntgt = KTOP - rem;

    // ---- compact: bins>T -> sSel[0..cntgt) (any order); bin==T -> sCand ----
    {
        uint32_t gtc = 0, eqc = 0;
        #pragma unroll
        for (int e = 0; e < CH; ++e) {
            uint32_t bin = key_bin(myk[e]);
            gtc += (bin > Tbin) ? 1u : 0u;
            eqc += (bin == Tbin) ? 1u : 0u;
        }
        uint32_t pack = (gtc << 16) | eqc;   // gt total <= 300, eq total <= 8400: no overflow
        uint32_t ps = pack;
        #pragma unroll
        for (int off = 1; off < 64; off <<= 1) {
            uint32_t o = __shfl_up(ps, off, 64);
            if (lane >= off) ps += o;
        }
        if (lane == 63) sWTot[wv] = ps;
        __syncthreads();
        uint32_t excl = ps - pack;           // exclusive within wave
        #pragma unroll
        for (int w2 = 0; w2 < 8; ++w2) if (w2 < wv) excl += sWTot[w2];
        uint32_t gtoff = excl >> 16;
        uint32_t eqoff = excl & 0xFFFFu;
        if (t == TB - 1) {
            uint32_t tot = eqoff + eqc;      // inclusive total of eq counts
            sCN = (tot > CANDMAX) ? CANDMAX : tot;
        }
        #pragma unroll
        for (int e = 0; e < CH; ++e) {
            uint32_t k = myk[e];
            uint32_t bin = key_bin(k);
            uint32_t idx = (uint32_t)(e * TB + t);
            if (bin > Tbin) {
                sSel[gtoff++] = ((ull)k << 32) | (ull)(0xFFFFFFFFu - idx);
            } else if (bin == Tbin) {
                if (eqoff < CANDMAX)
                    sCand[eqoff] = ((ull)k << 32) | (ull)(0xFFFFFFFFu - idx);
                eqoff++;
            }
        }
        __syncthreads();
    }

    // ---- candidate mini-rank: exact (key desc, idx asc); top rem fill sSel tail ----
    {
        int cn = (int)sCN;                   // expected ~27
        if (t < cn) {
            ull my = sCand[t];
            uint32_t rk = 0;
            for (int j = 0; j < cn; ++j) rk += (sCand[j] > my) ? 1u : 0u;
            if (rk < rem) sSel[cntgt + rk] = my;
        }
        __syncthreads();
    }

    // ---- fused gather + exact rank: 2 threads/row; b128 rank reads; global hides LDS ----
    const size_t bo = (size_t)b * KTOP;
    const ulonglong2* sSel2 = (const ulonglong2*)sSel;   // 150 aligned pairs
    for (int tt = t; tt < 2 * KTOP; tt += TB) {   // pairs (2k,2k+1) same wave & iteration
        const int row = tt >> 1;
        const int half = tt & 1;
        const ull selv = sSel[row];
        const uint32_t a = 0xFFFFFFFFu - (uint32_t)selv;
        const float* p = pred + ((size_t)b * NA + a) * 85;
        const int cbase = half * 40;
        float v0 = p[5 + cbase], v1 = p[6 + cbase], v2 = p[7 + cbase], v3 = p[8 + cbase];
        int   c0 = cbase, c1 = cbase + 1, c2 = cbase + 2, c3 = cbase + 3;
        #pragma unroll
        for (int c = 4; c < 40; c += 4) {
            float w0 = p[5 + cbase + c],     w1 = p[6 + cbase + c];
            float w2 = p[7 + cbase + c],     w3 = p[8 + cbase + c];
            if (w0 > v0) { v0 = w0; c0 = cbase + c; }        // strict >: first-in-stream
            if (w1 > v1) { v1 = w1; c1 = cbase + c + 1; }
            if (w2 > v2) { v2 = w2; c2 = cbase + c + 2; }
            if (w3 > v3) { v3 = w3; c3 = cbase + c + 3; }
        }
        // rank half: half 0 counts j=0..149, half 1 counts j=150..299 (75 b128 reads)
        uint32_t rk = 0;
        const int pb = half * 75;
        for (int jp = pb; jp < pb + 75; ++jp) {
            ulonglong2 vv = sSel2[jp];
            rk += (vv.x > selv) ? 1u : 0u;
            rk += (vv.y > selv) ? 1u : 0u;
        }
        // combine streams with index tie-break -> exact argmax-first
        float bv = v0; int bc = c0;
        if (v1 > bv || (v1 == bv && c1 < bc)) { bv = v1; bc = c1; }
        if (v2 > bv || (v2 == bv && c2 < bc)) { bv = v2; bc = c2; }
        if (v3 > bv || (v3 == bv && c3 < bc)) { bv = v3; bc = c3; }
        float pv = __shfl_xor(bv, 1, 64);
        int   pc = __shfl_xor(bc, 1, 64);
        uint32_t rko = __shfl_xor(rk, 1, 64);
        const uint32_t rank = rk + rko;
        if (half == 0) {
            if (pv > bv) { bv = pv; bc = pc; }   // partner indices larger: tie keeps ours
            float x = p[0], y = p[1], w = p[2], h = p[3], obj = p[4];
            float hw = w * 0.5f, hh = h * 0.5f;
            float x1 = x - hw, y1 = y - hh, x2 = x + hw, y2 = y + hh;
            sSorted[rank] = selv;
            sBox[rank] = make_float4(x1, y1, x2, y2);
            sA[rank] = fmaxf(x2 - x1, 0.0f) * fmaxf(y2 - y1, 0.0f);  // same expr as ref
            out[(bo + rank) * 4 + 0] = y1;
            out[(bo + rank) * 4 + 1] = x1;
            out[(bo + rank) * 4 + 2] = y2;
            out[(bo + rank) * 4 + 3] = x2;
            out[O4 + (bo + rank) * 2 + 0] = (y1 + y2) * 0.5f;
            out[O4 + (bo + rank) * 2 + 1] = (x1 + x2) * 0.5f;
            out[O2 + bo + rank] = fmaxf(obj, bv);
            out[O3 + bo + rank] = (float)bc;
        }
    }
    __syncthreads();

    // ---- IoU masks: 375 tiles of 4 i-rows x 64 j (1 b128 + 1 b32 per j, amortized 4x) ----
    if (t < 375) {
        const int role = t / 75;
        const int i0 = (t - role * 75) * 4;
        const int j0 = role * 64;
        int jmax = j0 + 64; if (jmax > KTOP) jmax = KTOP;
        float4 bi0 = sBox[i0],     bi1 = sBox[i0 + 1];
        float4 bi2 = sBox[i0 + 2], bi3 = sBox[i0 + 3];
        float a0 = sA[i0], a1 = sA[i0 + 1], a2 = sA[i0 + 2], a3 = sA[i0 + 3];
        ull bits0 = 0ull, bits1 = 0ull, bits2 = 0ull, bits3 = 0ull;
        if (jmax > i0 + 1) {                 // else the whole tile is below the diagonal
            for (int j = j0; j < jmax; ++j) {
                float4 bj = sBox[j];         // broadcast b128
                float aj = sA[j];            // broadcast b32
                ull bit = 1ull << (j - j0);
                {   // i0
                    float iw = fminf(bi0.z, bj.z) - fmaxf(bi0.x, bj.x); iw = fmaxf(iw, 0.0f);
                    float ih = fminf(bi0.w, bj.w) - fmaxf(bi0.y, bj.y); ih = fmaxf(ih, 0.0f);
                    float inter = iw * ih;
                    float den = a0 + aj; den = den - inter; den = den + 1e-9f;
                    if (j > i0 && inter / den > 0.45f) bits0 |= bit;
                }
                {   // i0+1
                    float iw = fminf(bi1.z, bj.z) - fmaxf(bi1.x, bj.x); iw = fmaxf(iw, 0.0f);
                    float ih = fminf(bi1.w, bj.w) - fmaxf(bi1.y, bj.y); ih = fmaxf(ih, 0.0f);
                    float inter = iw * ih;
                    float den = a1 + aj; den = den - inter; den = den + 1e-9f;
                    if (j > i0 + 1 && inter / den > 0.45f) bits1 |= bit;
                }
                {   // i0+2
                    float iw = fminf(bi2.z, bj.z) - fmaxf(bi2.x, bj.x); iw = fmaxf(iw, 0.0f);
                    float ih = fminf(bi2.w, bj.w) - fmaxf(bi2.y, bj.y); ih = fmaxf(ih, 0.0f);
                    float inter = iw * ih;
                    float den = a2 + aj; den = den - inter; den = den + 1e-9f;
                    if (j > i0 + 2 && inter / den > 0.45f) bits2 |= bit;
                }
                {   // i0+3
                    float iw = fminf(bi3.z, bj.z) - fmaxf(bi3.x, bj.x); iw = fmaxf(iw, 0.0f);
                    float ih = fminf(bi3.w, bj.w) - fmaxf(bi3.y, bj.y); ih = fmaxf(ih, 0.0f);
                    float inter = iw * ih;
                    float den = a3 + aj; den = den - inter; den = den + 1e-9f;
                    if (j > i0 + 3 && inter / den > 0.45f) bits3 |= bit;
                }
            }
        }
        sMask[(i0 + 0) * 5 + role] = bits0;
        sMask[(i0 + 1) * 5 + role] = bits1;
        sMask[(i0 + 2) * 5 + role] = bits2;
        sMask[(i0 + 3) * 5 + role] = bits3;
    }
    __syncthreads();

    // ---- wave 0: greedy NMS.  waves 1-5 (independent): zone parity ----
    if (wv == 0) {
        ull rm[5][5];
        ull kw[5];
        #pragma unroll
        for (int w = 0; w < 5; ++w) {
            int i = w * 64 + lane;
            bool f = (i < KTOP) && (((uint32_t)(sSorted[i] >> 32)) > 0x007FFFFFu);
            kw[w] = __ballot(f);             // keep-init, replicated in every lane
            #pragma unroll
            for (int ww = 0; ww < 5; ++ww)
                rm[w][ww] = (i < KTOP) ? sMask[i * 5 + ww] : 0ull;
        }
        #pragma unroll
        for (int w = 0; w < 5; ++w) {
            ull cur = kw[w];
            while (cur) {
                int ib = __builtin_ctzll(cur);          // accepted box i = w*64+ib
                ull m0 = __shfl(rm[w][0], ib);
                ull m1 = __shfl(rm[w][1], ib);
                ull m2 = __shfl(rm[w][2], ib);
                ull m3 = __shfl(rm[w][3], ib);
                ull m4 = __shfl(rm[w][4], ib);
                kw[0] &= ~m0; kw[1] &= ~m1; kw[2] &= ~m2; kw[3] &= ~m3; kw[4] &= ~m4;
                ull done = (ib == 63) ? 0ull : (~0ull << (ib + 1));
                cur = kw[w] & done;
            }
        }
        if (lane == 0) {
            #pragma unroll
            for (int w = 0; w < 5; ++w) sKeepF[w] = kw[w];
        }
    } else if (t >= 64 && t < 64 + KTOP) {
        const int i = t - 64;
        float4 bi = sBox[i];
        float cy = (bi.y + bi.w) * 0.5f;     // bit-identical to stored centers
        float cx = (bi.x + bi.z) * 0.5f;
        int cnt = 0;
        #pragma unroll
        for (int e = 0; e < 8; ++e) {
            float xi = sZone[2 * e], yi = sZone[2 * e + 1];
            int ep = (e + 7) & 7;               // zr = roll(zone, 1)
            float xj = sZone[2 * ep], yj = sZone[2 * ep + 1];
            bool gyi = yi > cy, gyj = yj > cy;
            if (gyi != gyj) {
                float gx = (xj - xi) * (cy - yi) / (yj - yi) + xi;
                if (gx > cx) cnt++;
            }
        }
        sPar[i] = (uint32_t)(cnt & 1);
    }
    __syncthreads();

    if (t < KTOP) {
        int kp = (int)((sKeepF[t >> 6] >> (t & 63)) & 1ull);
        int inz = (sPar[t] && kp) ? 1 : 0;
        out[O1 + bo + t] = (float)inz;
        out[O5 + bo + t] = (float)kp;
    }
}

extern "C" void kernel_launch(void* const* d_in, const int* in_sizes, int n_in,
                              void* d_out, int out_size, void* d_ws, size_t ws_size,
                              hipStream_t stream) {
    const float* pred = (const float*)d_in[0];   // (32,8400,85) fp32
    const float* zone = (const float*)d_in[1];   // (8,2) fp32
    float* out = (float*)d_out;                  // 96000 fp32
    uint32_t* keys = (uint32_t*)d_ws;            // 32*8400 u32 = 1.075 MB

    score_kernel<<<(NB * NA) / 128, 256, 0, stream>>>(pred, keys);
    batch_kernel<<<NB, TB, 0, stream>>>(pred, zone, keys, out);
}

// Round 10
// 228.370 us; speedup vs baseline: 1.0020x; 1.0020x over previous
//
#include <hip/hip_runtime.h>
#include <stdint.h>

typedef unsigned long long ull;

#define NA 8400
#define NB 32
#define KTOP 300
#define NC 80
#define TB 512         // 8 waves; launch_bounds(TB,1): grid=1 block/CU, so let the
                       // allocator use the full VGPR budget instead of spilling (R8/R9 lesson)
#define CH 17          // 512*17 = 8704 >= 8400; keys live in registers
#define NBIN 309       // 1 underflow bin + 307 score bins + margin
#define HSTR 311       // odd stride: copies of one bin staggered across banks
#define NCPY 8         // histogram copies (one per wave)
#define BASEK 0xBE4CCCCDu   // bits of 0.2f with sign-flag set (keys are score-bits | 0x80000000)
#define CANDMAX 512

// out layout: boxes_yxyx @0 ; in_zone @38400 ; scores @48000 ; classes @57600 ;
//             centers_yx @67200 ; keep @86400 ; total 96000 floats
#define O1 38400
#define O2 48000
#define O3 57600
#define O4 67200
#define O5 86400

// ---------------- A: per-anchor score key (memory-bound, unchanged) ----------------
__global__ __launch_bounds__(256) void score_kernel(const float* __restrict__ pred,
                                                    uint32_t* __restrict__ keys) {
    __shared__ float sP[128 * 85];
    const int blk = blockIdx.x;                       // 2100 blocks * 128 anchors
    const float4* g4 = (const float4*)(pred + (size_t)blk * 128 * 85);
    float4* l4 = (float4*)sP;
    for (int i = threadIdx.x; i < (128 * 85 / 4); i += 256) l4[i] = g4[i];
    __syncthreads();
    const int t = threadIdx.x;
    if (t < 128) {
        const float* p = sP + t * 85;
        float obj = p[4];
        float b0 = p[5], b1 = p[6], b2 = p[7], b3 = p[8];
        #pragma unroll
        for (int c = 4; c < NC; c += 4) {
            b0 = fmaxf(b0, p[5 + c]);
            b1 = fmaxf(b1, p[6 + c]);
            b2 = fmaxf(b2, p[7 + c]);
            b3 = fmaxf(b3, p[8 + c]);
        }
        float best = fmaxf(fmaxf(b0, b1), fmaxf(b2, b3));
        float sc = obj * best;
        uint32_t u = (sc >= 0.2f) ? (__float_as_uint(sc) | 0x80000000u) : 0x007FFFFFu;
        keys[(size_t)blk * 128 + t] = u;
    }
}

__device__ __forceinline__ uint32_t key_bin(uint32_t k) {
    return (k < BASEK) ? 0u : (1u + ((k - BASEK) >> 16));   // max 308 < NBIN
}

// ---------------- B: one block per batch: select + sort + gather + IoU + NMS ----------------
__global__ __launch_bounds__(TB, 1) void batch_kernel(const float* __restrict__ pred,
                                                      const float* __restrict__ zone,
                                                      const uint32_t* __restrict__ keys,
                                                      float* __restrict__ out) {
    #pragma clang fp contract(off)
    __shared__ uint32_t sH[NCPY * HSTR];
    __shared__ __align__(16) ull sSel[KTOP];
    __shared__ ull sSorted[KTOP];
    __shared__ ull sCand[CANDMAX];
    __shared__ float4 sBox[KTOP];       // (x1,y1,x2,y2) per sorted box
    __shared__ float sA[KTOP];          // precomputed clamped area (same expression as ref)
    __shared__ ull sMask[KTOP * 5];
    __shared__ uint32_t sWTot[8];
    __shared__ uint32_t sBc[2];
    __shared__ uint32_t sPar[KTOP];
    __shared__ ull sKeepF[5];
    __shared__ float sZone[16];
    __shared__ uint32_t sCN;

    const int b = blockIdx.x;
    const int t = threadIdx.x;
    const int lane = t & 63;
    const int wv = t >> 6;              // 0..7; also the histogram copy id

    // ---- coalesced key load into registers (pads -> key 0 -> bin 0, never selected) ----
    uint32_t myk[CH];
    #pragma unroll
    for (int e = 0; e < CH; ++e) {
        int idx = e * TB + t;
        myk[e] = (idx < NA) ? keys[(size_t)b * NA + idx] : 0u;
    }
    for (int i = t; i < NCPY * HSTR; i += TB) sH[i] = 0u;
    if (t < 16) sZone[t] = zone[t];
    __syncthreads();

    // ---- one-shot dense histogram (8 copies, one per wave) ----
    // bin 0 (below-threshold, ~20% of keys, SAME address) via ballot+popc: one atomic/wave
    {
        uint32_t* hw = &sH[wv * HSTR];
        uint32_t c0 = 0;
        #pragma unroll
        for (int e = 0; e < CH; ++e) {
            uint32_t k = myk[e];
            ull m = __ballot(k < BASEK);
            c0 += (uint32_t)__popcll(m);
            if (k >= BASEK)
                atomicAdd(&hw[1u + ((k - BASEK) >> 16)], 1u);
        }
        if (lane == 0) atomicAdd(&hw[0], c0);
    }
    __syncthreads();

    // ---- suffix scan over 309 bins (waves 0..4), find threshold bin ----
    uint32_t v = 0, s = 0;
    if (t < 320) {
        if (t < NBIN) {
            #pragma unroll
            for (int c = 0; c < NCPY; ++c) v += sH[c * HSTR + t];
        }
        s = v;
        #pragma unroll
        for (int off = 1; off < 64; off <<= 1) {
            uint32_t o = __shfl_down(s, off, 64);
            if (lane + off < 64) s += o;
        }
        if (lane == 0) sWTot[wv] = s;
    }
    __syncthreads();
    if (t < 320) {
        uint32_t S = s;
        for (int w2 = wv + 1; w2 < 5; ++w2) S += sWTot[w2];
        uint32_t above = S - v;              // keys in bins strictly above t
        if (above < KTOP && S >= KTOP) {     // unique crossing bin
            sBc[0] = (uint32_t)t;
            sBc[1] = KTOP - above;
        }
    }
    __syncthreads();
    const uint32_t Tbin = sBc[0];
    const uint32_t rem = sBc[1];             // how many to take from bin Tbin
    const uint32_t cntgt = KTOP - rem;

    // ---- compact: bins>T -> sSel[0..cntgt) (any order); bin==T -> sCand ----
    {
        uint32_t gtc = 0, eqc = 0;
        #pragma unroll
        for (int e = 0; e < CH; ++e) {
            uint32_t bin = key_bin(myk[e]);
            gtc += (bin > Tbin) ? 1u : 0u;
            eqc += (bin == Tbin) ? 1u : 0u;
        }
        uint32_t pack = (gtc << 16) | eqc;   // gt total <= 300, eq total <= 8400: no overflow
        uint32_t ps = pack;
        #pragma unroll
        for (int off = 1; off < 64; off <<= 1) {
            uint32_t o = __shfl_up(ps, off, 64);
            if (lane >= off) ps += o;
        }
        if (lane == 63) sWTot[wv] = ps;
        __syncthreads();
        uint32_t excl = ps - pack;           // exclusive within wave
        #pragma unroll
        for (int w2 = 0; w2 < 8; ++w2) if (w2 < wv) excl += sWTot[w2];
        uint32_t gtoff = excl >> 16;
        uint32_t eqoff = excl & 0xFFFFu;
        if (t == TB - 1) {
            uint32_t tot = eqoff + eqc;      // inclusive total of eq counts
            sCN = (tot > CANDMAX) ? CANDMAX : tot;
        }
        #pragma unroll
        for (int e = 0; e < CH; ++e) {
            uint32_t k = myk[e];
            uint32_t bin = key_bin(k);
            uint32_t idx = (uint32_t)(e * TB + t);
            if (bin > Tbin) {
                sSel[gtoff++] = ((ull)k << 32) | (ull)(0xFFFFFFFFu - idx);
            } else if (bin == Tbin) {
                if (eqoff < CANDMAX)
                    sCand[eqoff] = ((ull)k << 32) | (ull)(0xFFFFFFFFu - idx);
                eqoff++;
            }
        }
        __syncthreads();
    }

    // ---- candidate mini-rank: exact (key desc, idx asc); top rem fill sSel tail ----
    {
        int cn = (int)sCN;                   // expected ~27
        if (t < cn) {
            ull my = sCand[t];
            uint32_t rk = 0;
            for (int j = 0; j < cn; ++j) rk += (sCand[j] > my) ? 1u : 0u;
            if (rk < rem) sSel[cntgt + rk] = my;
        }
        __syncthreads();
    }

    // ---- fused gather + exact rank: 2 threads/row; b128 rank reads; global hides LDS ----
    const size_t bo = (size_t)b * KTOP;
    const ulonglong2* sSel2 = (const ulonglong2*)sSel;   // 150 aligned pairs
    for (int tt = t; tt < 2 * KTOP; tt += TB) {   // pairs (2k,2k+1) same wave & iteration
        const int row = tt >> 1;
        const int half = tt & 1;
        const ull selv = sSel[row];
        const uint32_t a = 0xFFFFFFFFu - (uint32_t)selv;
        const float* p = pred + ((size_t)b * NA + a) * 85;
        const int cbase = half * 40;
        float v0 = p[5 + cbase], v1 = p[6 + cbase], v2 = p[7 + cbase], v3 = p[8 + cbase];
        int   c0 = cbase, c1 = cbase + 1, c2 = cbase + 2, c3 = cbase + 3;
        #pragma unroll
        for (int c = 4; c < 40; c += 4) {
            float w0 = p[5 + cbase + c],     w1 = p[6 + cbase + c];
            float w2 = p[7 + cbase + c],     w3 = p[8 + cbase + c];
            if (w0 > v0) { v0 = w0; c0 = cbase + c; }        // strict >: first-in-stream
            if (w1 > v1) { v1 = w1; c1 = cbase + c + 1; }
            if (w2 > v2) { v2 = w2; c2 = cbase + c + 2; }
            if (w3 > v3) { v3 = w3; c3 = cbase + c + 3; }
        }
        // rank half: half 0 counts j=0..149, half 1 counts j=150..299 (75 b128 reads)
        uint32_t rk = 0;
        const int pb = half * 75;
        for (int jp = pb; jp < pb + 75; ++jp) {
            ulonglong2 vv = sSel2[jp];
            rk += (vv.x > selv) ? 1u : 0u;
            rk += (vv.y > selv) ? 1u : 0u;
        }
        // combine streams with index tie-break -> exact argmax-first
        float bv = v0; int bc = c0;
        if (v1 > bv || (v1 == bv && c1 < bc)) { bv = v1; bc = c1; }
        if (v2 > bv || (v2 == bv && c2 < bc)) { bv = v2; bc = c2; }
        if (v3 > bv || (v3 == bv && c3 < bc)) { bv = v3; bc = c3; }
        float pv = __shfl_xor(bv, 1, 64);
        int   pc = __shfl_xor(bc, 1, 64);
        uint32_t rko = __shfl_xor(rk, 1, 64);
        const uint32_t rank = rk + rko;
        if (half == 0) {
            if (pv > bv) { bv = pv; bc = pc; }   // partner indices larger: tie keeps ours
            float x = p[0], y = p[1], w = p[2], h = p[3], obj = p[4];
            float hw = w * 0.5f, hh = h * 0.5f;
            float x1 = x - hw, y1 = y - hh, x2 = x + hw, y2 = y + hh;
            sSorted[rank] = selv;
            sBox[rank] = make_float4(x1, y1, x2, y2);
            sA[rank] = fmaxf(x2 - x1, 0.0f) * fmaxf(y2 - y1, 0.0f);  // same expr as ref
            out[(bo + rank) * 4 + 0] = y1;
            out[(bo + rank) * 4 + 1] = x1;
            out[(bo + rank) * 4 + 2] = y2;
            out[(bo + rank) * 4 + 3] = x2;
            out[O4 + (bo + rank) * 2 + 0] = (y1 + y2) * 0.5f;
            out[O4 + (bo + rank) * 2 + 1] = (x1 + x2) * 0.5f;
            out[O2 + bo + rank] = fmaxf(obj, bv);
            out[O3 + bo + rank] = (float)bc;
        }
    }
    __syncthreads();

    // ---- IoU masks: 375 tiles of 4 i-rows x 64 j (1 b128 + 1 b32 per j, amortized 4x) ----
    if (t < 375) {
        const int role = t / 75;
        const int i0 = (t - role * 75) * 4;
        const int j0 = role * 64;
        int jmax = j0 + 64; if (jmax > KTOP) jmax = KTOP;
        float4 bi0 = sBox[i0],     bi1 = sBox[i0 + 1];
        float4 bi2 = sBox[i0 + 2], bi3 = sBox[i0 + 3];
        float a0 = sA[i0], a1 = sA[i0 + 1], a2 = sA[i0 + 2], a3 = sA[i0 + 3];
        ull bits0 = 0ull, bits1 = 0ull, bits2 = 0ull, bits3 = 0ull;
        if (jmax > i0 + 1) {                 // else the whole tile is below the diagonal
            for (int j = j0; j < jmax; ++j) {
                float4 bj = sBox[j];         // broadcast b128
                float aj = sA[j];            // broadcast b32
                ull bit = 1ull << (j - j0);
                {   // i0
                    float iw = fminf(bi0.z, bj.z) - fmaxf(bi0.x, bj.x); iw = fmaxf(iw, 0.0f);
                    float ih = fminf(bi0.w, bj.w) - fmaxf(bi0.y, bj.y); ih = fmaxf(ih, 0.0f);
                    float inter = iw * ih;
                    float den = a0 + aj; den = den - inter; den = den + 1e-9f;
                    if (j > i0 && inter / den > 0.45f) bits0 |= bit;
                }
                {   // i0+1
                    float iw = fminf(bi1.z, bj.z) - fmaxf(bi1.x, bj.x); iw = fmaxf(iw, 0.0f);
                    float ih = fminf(bi1.w, bj.w) - fmaxf(bi1.y, bj.y); ih = fmaxf(ih, 0.0f);
                    float inter = iw * ih;
                    float den = a1 + aj; den = den - inter; den = den + 1e-9f;
                    if (j > i0 + 1 && inter / den > 0.45f) bits1 |= bit;
                }
                {   // i0+2
                    float iw = fminf(bi2.z, bj.z) - fmaxf(bi2.x, bj.x); iw = fmaxf(iw, 0.0f);
                    float ih = fminf(bi2.w, bj.w) - fmaxf(bi2.y, bj.y); ih = fmaxf(ih, 0.0f);
                    float inter = iw * ih;
                    float den = a2 + aj; den = den - inter; den = den + 1e-9f;
                    if (j > i0 + 2 && inter / den > 0.45f) bits2 |= bit;
                }
                {   // i0+3
                    float iw = fminf(bi3.z, bj.z) - fmaxf(bi3.x, bj.x); iw = fmaxf(iw, 0.0f);
                    float ih = fminf(bi3.w, bj.w) - fmaxf(bi3.y, bj.y); ih = fmaxf(ih, 0.0f);
                    float inter = iw * ih;
                    float den = a3 + aj; den = den - inter; den = den + 1e-9f;
                    if (j > i0 + 3 && inter / den > 0.45f) bits3 |= bit;
                }
            }
        }
        sMask[(i0 + 0) * 5 + role] = bits0;
        sMask[(i0 + 1) * 5 + role] = bits1;
        sMask[(i0 + 2) * 5 + role] = bits2;
        sMask[(i0 + 3) * 5 + role] = bits3;
    }
    __syncthreads();

    // ---- wave 0: greedy NMS.  waves 1-5 (independent): zone parity ----
    if (wv == 0) {
        ull rm[5][5];
        ull kw[5];
        #pragma unroll
        for (int w = 0; w < 5; ++w) {
            int i = w * 64 + lane;
            bool f = (i < KTOP) && (((uint32_t)(sSorted[i] >> 32)) > 0x007FFFFFu);
            kw[w] = __ballot(f);             // keep-init, replicated in every lane
            #pragma unroll
            for (int ww = 0; ww < 5; ++ww)
                rm[w][ww] = (i < KTOP) ? sMask[i * 5 + ww] : 0ull;
        }
        #pragma unroll
        for (int w = 0; w < 5; ++w) {
            ull cur = kw[w];
            while (cur) {
                int ib = __builtin_ctzll(cur);          // accepted box i = w*64+ib
                ull m0 = __shfl(rm[w][0], ib);
                ull m1 = __shfl(rm[w][1], ib);
                ull m2 = __shfl(rm[w][2], ib);
                ull m3 = __shfl(rm[w][3], ib);
                ull m4 = __shfl(rm[w][4], ib);
                kw[0] &= ~m0; kw[1] &= ~m1; kw[2] &= ~m2; kw[3] &= ~m3; kw[4] &= ~m4;
                ull done = (ib == 63) ? 0ull : (~0ull << (ib + 1));
                cur = kw[w] & done;
            }
        }
        if (lane == 0) {
            #pragma unroll
            for (int w = 0; w < 5; ++w) sKeepF[w] = kw[w];
        }
    } else if (t >= 64 && t < 64 + KTOP) {
        const int i = t - 64;
        float4 bi = sBox[i];
        float cy = (bi.y + bi.w) * 0.5f;     // bit-identical to stored centers
        float cx = (bi.x + bi.z) * 0.5f;
        int cnt = 0;
        #pragma unroll
        for (int e = 0; e < 8; ++e) {
            float xi = sZone[2 * e], yi = sZone[2 * e + 1];
            int ep = (e + 7) & 7;               // zr = roll(zone, 1)
            float xj = sZone[2 * ep], yj = sZone[2 * ep + 1];
            bool gyi = yi > cy, gyj = yj > cy;
            if (gyi != gyj) {
                float gx = (xj - xi) * (cy - yi) / (yj - yi) + xi;
                if (gx > cx) cnt++;
            }
        }
        sPar[i] = (uint32_t)(cnt & 1);
    }
    __syncthreads();

    if (t < KTOP) {
        int kp = (int)((sKeepF[t >> 6] >> (t & 63)) & 1ull);
        int inz = (sPar[t] && kp) ? 1 : 0;
        out[O1 + bo + t] = (float)inz;
        out[O5 + bo + t] = (float)kp;
    }
}

extern "C" void kernel_launch(void* const* d_in, const int* in_sizes, int n_in,
                              void* d_out, int out_size, void* d_ws, size_t ws_size,
                              hipStream_t stream) {
    const float* pred = (const float*)d_in[0];   // (32,8400,85) fp32
    const float* zone = (const float*)d_in[1];   // (8,2) fp32
    float* out = (float*)d_out;                  // 96000 fp32
    uint32_t* keys = (uint32_t*)d_ws;            // 32*8400 u32 = 1.075 MB

    score_kernel<<<(NB * NA) / 128, 256, 0, stream>>>(pred, keys);
    batch_kernel<<<NB, TB, 0, stream>>>(pred, zone, keys, out);
}

// Round 11
// 183.696 us; speedup vs baseline: 1.2456x; 1.2432x over previous
//
#include <hip/hip_runtime.h>
#include <stdint.h>

typedef unsigned long long ull;

#define NA 8400
#define NB 32
#define KTOP 300
#define NC 80
#define TB 512         // 8 waves; plain launch_bounds: R7 config (VGPR 64, no spill)
#define CH 17          // 512*17 = 8704 >= 8400; keys live in registers
#define NBIN 309       // 1 underflow bin + 307 score bins + margin
#define HSTR 311       // odd stride: copies of one bin staggered across banks
#define NCPY 8         // histogram copies (one per wave)
#define BASEK 0xBE4CCCCDu   // bits of 0.2f with sign-flag set (keys are score-bits | 0x80000000)
#define CANDMAX 512

// out layout: boxes_yxyx @0 ; in_zone @38400 ; scores @48000 ; classes @57600 ;
//             centers_yx @67200 ; keep @86400 ; total 96000 floats
#define O1 38400
#define O2 48000
#define O3 57600
#define O4 67200
#define O5 86400

// ---------------- A: per-anchor score key (memory-bound, unchanged) ----------------
__global__ __launch_bounds__(256) void score_kernel(const float* __restrict__ pred,
                                                    uint32_t* __restrict__ keys) {
    __shared__ float sP[128 * 85];
    const int blk = blockIdx.x;                       // 2100 blocks * 128 anchors
    const float4* g4 = (const float4*)(pred + (size_t)blk * 128 * 85);
    float4* l4 = (float4*)sP;
    for (int i = threadIdx.x; i < (128 * 85 / 4); i += 256) l4[i] = g4[i];
    __syncthreads();
    const int t = threadIdx.x;
    if (t < 128) {
        const float* p = sP + t * 85;
        float obj = p[4];
        float b0 = p[5], b1 = p[6], b2 = p[7], b3 = p[8];
        #pragma unroll
        for (int c = 4; c < NC; c += 4) {
            b0 = fmaxf(b0, p[5 + c]);
            b1 = fmaxf(b1, p[6 + c]);
            b2 = fmaxf(b2, p[7 + c]);
            b3 = fmaxf(b3, p[8 + c]);
        }
        float best = fmaxf(fmaxf(b0, b1), fmaxf(b2, b3));
        float sc = obj * best;
        uint32_t u = (sc >= 0.2f) ? (__float_as_uint(sc) | 0x80000000u) : 0x007FFFFFu;
        keys[(size_t)blk * 128 + t] = u;
    }
}

__device__ __forceinline__ uint32_t key_bin(uint32_t k) {
    return (k < BASEK) ? 0u : (1u + ((k - BASEK) >> 16));   // max 308 < NBIN
}

// ---------------- B: one block per batch: select + sort + gather + IoU + NMS ----------------
__global__ __launch_bounds__(TB) void batch_kernel(const float* __restrict__ pred,
                                                   const float* __restrict__ zone,
                                                   const uint32_t* __restrict__ keys,
                                                   float* __restrict__ out) {
    #pragma clang fp contract(off)
    __shared__ uint32_t sH[NCPY * HSTR];
    __shared__ __align__(16) ull sSel[KTOP];
    __shared__ ull sSorted[KTOP];
    __shared__ ull sCand[CANDMAX];
    __shared__ float4 sBox[KTOP];       // (x1,y1,x2,y2) per sorted box
    __shared__ float sA[KTOP];          // precomputed clamped area (same expression as ref)
    __shared__ ull sMask[KTOP * 5];
    __shared__ uint32_t sWTot[8];
    __shared__ uint32_t sBc[2];
    __shared__ uint32_t sPar[KTOP];
    __shared__ ull sKeepF[5];
    __shared__ float sZone[16];
    __shared__ uint32_t sCN;

    const int b = blockIdx.x;
    const int t = threadIdx.x;
    const int lane = t & 63;
    const int wv = t >> 6;              // 0..7; also the histogram copy id

    // ---- coalesced key load into registers (pads -> key 0 -> bin 0, never selected) ----
    uint32_t myk[CH];
    #pragma unroll
    for (int e = 0; e < CH; ++e) {
        int idx = e * TB + t;
        myk[e] = (idx < NA) ? keys[(size_t)b * NA + idx] : 0u;
    }
    for (int i = t; i < NCPY * HSTR; i += TB) sH[i] = 0u;
    if (t < 16) sZone[t] = zone[t];
    __syncthreads();

    // ---- one-shot dense histogram (8 copies, one per wave) ----
    // bin 0 (below-threshold, ~20% of keys, SAME address) via ballot+popc: one atomic/wave
    {
        uint32_t* hw = &sH[wv * HSTR];
        uint32_t c0 = 0;
        #pragma unroll
        for (int e = 0; e < CH; ++e) {
            uint32_t k = myk[e];
            ull m = __ballot(k < BASEK);
            c0 += (uint32_t)__popcll(m);
            if (k >= BASEK)
                atomicAdd(&hw[1u + ((k - BASEK) >> 16)], 1u);
        }
        if (lane == 0) atomicAdd(&hw[0], c0);
    }
    __syncthreads();

    // ---- suffix scan over 309 bins (waves 0..4), find threshold bin ----
    uint32_t v = 0, s = 0;
    if (t < 320) {
        if (t < NBIN) {
            #pragma unroll
            for (int c = 0; c < NCPY; ++c) v += sH[c * HSTR + t];
        }
        s = v;
        #pragma unroll
        for (int off = 1; off < 64; off <<= 1) {
            uint32_t o = __shfl_down(s, off, 64);
            if (lane + off < 64) s += o;
        }
        if (lane == 0) sWTot[wv] = s;
    }
    __syncthreads();
    if (t < 320) {
        uint32_t S = s;
        for (int w2 = wv + 1; w2 < 5; ++w2) S += sWTot[w2];
        uint32_t above = S - v;              // keys in bins strictly above t
        if (above < KTOP && S >= KTOP) {     // unique crossing bin
            sBc[0] = (uint32_t)t;
            sBc[1] = KTOP - above;
        }
    }
    __syncthreads();
    const uint32_t Tbin = sBc[0];
    const uint32_t rem = sBc[1];             // how many to take from bin Tbin
    const uint32_t cntgt = KTOP - rem;

    // ---- compact: bins>T -> sSel[0..cntgt) (any order); bin==T -> sCand ----
    {
        uint32_t gtc = 0, eqc = 0;
        #pragma unroll
        for (int e = 0; e < CH; ++e) {
            uint32_t bin = key_bin(myk[e]);
            gtc += (bin > Tbin) ? 1u : 0u;
            eqc += (bin == Tbin) ? 1u : 0u;
        }
        uint32_t pack = (gtc << 16) | eqc;   // gt total <= 300, eq total <= 8400: no overflow
        uint32_t ps = pack;
        #pragma unroll
        for (int off = 1; off < 64; off <<= 1) {
            uint32_t o = __shfl_up(ps, off, 64);
            if (lane >= off) ps += o;
        }
        if (lane == 63) sWTot[wv] = ps;
        __syncthreads();
        uint32_t excl = ps - pack;           // exclusive within wave
        #pragma unroll
        for (int w2 = 0; w2 < 8; ++w2) if (w2 < wv) excl += sWTot[w2];
        uint32_t gtoff = excl >> 16;
        uint32_t eqoff = excl & 0xFFFFu;
        if (t == TB - 1) {
            uint32_t tot = eqoff + eqc;      // inclusive total of eq counts
            sCN = (tot > CANDMAX) ? CANDMAX : tot;
        }
        #pragma unroll
        for (int e = 0; e < CH; ++e) {
            uint32_t k = myk[e];
            uint32_t bin = key_bin(k);
            uint32_t idx = (uint32_t)(e * TB + t);
            if (bin > Tbin) {
                sSel[gtoff++] = ((ull)k << 32) | (ull)(0xFFFFFFFFu - idx);
            } else if (bin == Tbin) {
                if (eqoff < CANDMAX)
                    sCand[eqoff] = ((ull)k << 32) | (ull)(0xFFFFFFFFu - idx);
                eqoff++;
            }
        }
        __syncthreads();
    }

    // ---- candidate mini-rank: exact (key desc, idx asc); top rem fill sSel tail ----
    {
        int cn = (int)sCN;                   // expected ~27
        if (t < cn) {
            ull my = sCand[t];
            uint32_t rk = 0;
            for (int j = 0; j < cn; ++j) rk += (sCand[j] > my) ? 1u : 0u;
            if (rk < rem) sSel[cntgt + rk] = my;
        }
        __syncthreads();
    }

    // ---- fused gather + exact rank: 2 threads/row (R7-proven structure) ----
    const size_t bo = (size_t)b * KTOP;
    for (int tt = t; tt < 2 * KTOP; tt += TB) {   // pairs (2k,2k+1) same wave & iteration
        const int row = tt >> 1;
        const int half = tt & 1;
        const ull selv = sSel[row];
        const uint32_t a = 0xFFFFFFFFu - (uint32_t)selv;
        const float* p = pred + ((size_t)b * NA + a) * 85;
        const int cbase = half * 40;
        float v0 = p[5 + cbase], v1 = p[6 + cbase], v2 = p[7 + cbase], v3 = p[8 + cbase];
        int   c0 = cbase, c1 = cbase + 1, c2 = cbase + 2, c3 = cbase + 3;
        #pragma unroll
        for (int c = 4; c < 40; c += 4) {
            float w0 = p[5 + cbase + c],     w1 = p[6 + cbase + c];
            float w2 = p[7 + cbase + c],     w3 = p[8 + cbase + c];
            if (w0 > v0) { v0 = w0; c0 = cbase + c; }        // strict >: first-in-stream
            if (w1 > v1) { v1 = w1; c1 = cbase + c + 1; }
            if (w2 > v2) { v2 = w2; c2 = cbase + c + 2; }
            if (w3 > v3) { v3 = w3; c3 = cbase + c + 3; }
        }
        // rank half: half 0 counts j=0..149, half 1 counts j=150..299 (broadcast reads)
        uint32_t rk = 0;
        const int jb = half * 150;
        for (int j = jb; j < jb + 150; ++j)
            rk += (sSel[j] > selv) ? 1u : 0u;
        // combine streams with index tie-break -> exact argmax-first
        float bv = v0; int bc = c0;
        if (v1 > bv || (v1 == bv && c1 < bc)) { bv = v1; bc = c1; }
        if (v2 > bv || (v2 == bv && c2 < bc)) { bv = v2; bc = c2; }
        if (v3 > bv || (v3 == bv && c3 < bc)) { bv = v3; bc = c3; }
        float pv = __shfl_xor(bv, 1, 64);
        int   pc = __shfl_xor(bc, 1, 64);
        uint32_t rko = __shfl_xor(rk, 1, 64);
        const uint32_t rank = rk + rko;
        if (half == 0) {
            if (pv > bv) { bv = pv; bc = pc; }   // partner indices larger: tie keeps ours
            float x = p[0], y = p[1], w = p[2], h = p[3], obj = p[4];
            float hw = w * 0.5f, hh = h * 0.5f;
            float x1 = x - hw, y1 = y - hh, x2 = x + hw, y2 = y + hh;
            sSorted[rank] = selv;
            sBox[rank] = make_float4(x1, y1, x2, y2);
            sA[rank] = fmaxf(x2 - x1, 0.0f) * fmaxf(y2 - y1, 0.0f);  // same expr as ref
            out[(bo + rank) * 4 + 0] = y1;
            out[(bo + rank) * 4 + 1] = x1;
            out[(bo + rank) * 4 + 2] = y2;
            out[(bo + rank) * 4 + 3] = x2;
            out[O4 + (bo + rank) * 2 + 0] = (y1 + y2) * 0.5f;
            out[O4 + (bo + rank) * 2 + 1] = (x1 + x2) * 0.5f;
            out[O2 + bo + rank] = fmaxf(obj, bv);
            out[O3 + bo + rank] = (float)bc;
        }
    }
    __syncthreads();

    // ---- IoU masks, role-major 1 row/thread (R7 structure), float4+sA reads ----
    for (int p2 = t; p2 < KTOP * 5; p2 += TB) {
        const int role = p2 / KTOP;
        const int i = p2 - role * KTOP;
        const int j0 = role * 64;
        int jmax = j0 + 64; if (jmax > KTOP) jmax = KTOP;
        if (jmax <= i + 1) { sMask[i * 5 + role] = 0ull; continue; }   // all j <= i: zero word
        float4 bi = sBox[i];
        float ai = sA[i];
        ull bits = 0ull;
        for (int j = j0; j < jmax; ++j) {
            float4 bj = sBox[j];             // broadcast b128
            float aj = sA[j];                // broadcast b32
            float iw = fminf(bi.z, bj.z) - fmaxf(bi.x, bj.x); iw = fmaxf(iw, 0.0f);
            float ih = fminf(bi.w, bj.w) - fmaxf(bi.y, bj.y); ih = fmaxf(ih, 0.0f);
            float inter = iw * ih;
            float den = ai + aj;             // mirror reference op order exactly
            den = den - inter;
            den = den + 1e-9f;
            float iou = inter / den;
            if (j > i && iou > 0.45f) bits |= (1ull << (j - j0));
        }
        sMask[i * 5 + role] = bits;
    }
    __syncthreads();

    // ---- wave 0: greedy NMS.  waves 1-5 (independent): zone parity ----
    if (wv == 0) {
        ull rm[5][5];
        ull kw[5];
        #pragma unroll
        for (int w = 0; w < 5; ++w) {
            int i = w * 64 + lane;
            bool f = (i < KTOP) && (((uint32_t)(sSorted[i] >> 32)) > 0x007FFFFFu);
            kw[w] = __ballot(f);             // keep-init, replicated in every lane
            #pragma unroll
            for (int ww = 0; ww < 5; ++ww)
                rm[w][ww] = (i < KTOP) ? sMask[i * 5 + ww] : 0ull;
        }
        #pragma unroll
        for (int w = 0; w < 5; ++w) {
            ull cur = kw[w];
            while (cur) {
                int ib = __builtin_ctzll(cur);          // accepted box i = w*64+ib
                ull m0 = __shfl(rm[w][0], ib);
                ull m1 = __shfl(rm[w][1], ib);
                ull m2 = __shfl(rm[w][2], ib);
                ull m3 = __shfl(rm[w][3], ib);
                ull m4 = __shfl(rm[w][4], ib);
                kw[0] &= ~m0; kw[1] &= ~m1; kw[2] &= ~m2; kw[3] &= ~m3; kw[4] &= ~m4;
                ull done = (ib == 63) ? 0ull : (~0ull << (ib + 1));
                cur = kw[w] & done;
            }
        }
        if (lane == 0) {
            #pragma unroll
            for (int w = 0; w < 5; ++w) sKeepF[w] = kw[w];
        }
    } else if (t >= 64 && t < 64 + KTOP) {
        const int i = t - 64;
        float4 bi = sBox[i];
        float cy = (bi.y + bi.w) * 0.5f;     // bit-identical to stored centers
        float cx = (bi.x + bi.z) * 0.5f;
        int cnt = 0;
        #pragma unroll
        for (int e = 0; e < 8; ++e) {
            float xi = sZone[2 * e], yi = sZone[2 * e + 1];
            int ep = (e + 7) & 7;               // zr = roll(zone, 1)
            float xj = sZone[2 * ep], yj = sZone[2 * ep + 1];
            bool gyi = yi > cy, gyj = yj > cy;
            if (gyi != gyj) {
                float gx = (xj - xi) * (cy - yi) / (yj - yi) + xi;
                if (gx > cx) cnt++;
            }
        }
        sPar[i] = (uint32_t)(cnt & 1);
    }
    __syncthreads();

    if (t < KTOP) {
        int kp = (int)((sKeepF[t >> 6] >> (t & 63)) & 1ull);
        int inz = (sPar[t] && kp) ? 1 : 0;
        out[O1 + bo + t] = (float)inz;
        out[O5 + bo + t] = (float)kp;
    }
}

extern "C" void kernel_launch(void* const* d_in, const int* in_sizes, int n_in,
                              void* d_out, int out_size, void* d_ws, size_t ws_size,
                              hipStream_t stream) {
    const float* pred = (const float*)d_in[0];   // (32,8400,85) fp32
    const float* zone = (const float*)d_in[1];   // (8,2) fp32
    float* out = (float*)d_out;                  // 96000 fp32
    uint32_t* keys = (uint32_t*)d_ws;            // 32*8400 u32 = 1.075 MB

    score_kernel<<<(NB * NA) / 128, 256, 0, stream>>>(pred, keys);
    batch_kernel<<<NB, TB, 0, stream>>>(pred, zone, keys, out);
}